// Round 9
// baseline (218.743 us; speedup 1.0000x reference)
//
#include <hip/hip_runtime.h>

#define N_NODES 10000
#define BN_TOT  40000
#define HID     64
#define IN_F    16
#define TCH     32
#define NW      12
#define RSTRIDE 192   // floats per row: [ch=64][t=3]  (768 B, contiguous per edge)

struct F3 { float x, y, z; };   // 12-byte packed triple -> global_load_dwordx3

// ---------------- histogram of dst (degree = cnt + 1) ------------------------
__global__ void hist_kernel(const int* __restrict__ dst, int* __restrict__ cnt, int E) {
    int e = blockIdx.x * blockDim.x + threadIdx.x;
    if (e < E) atomicAdd(&cnt[dst[e]], 1);
}

// ---------------- single-block exclusive scan over 10000 bins ----------------
__global__ __launch_bounds__(1024) void scan_kernel(const int* __restrict__ cnt,
                                                    int* __restrict__ row_ptr,
                                                    int* __restrict__ fill_pos,
                                                    float* __restrict__ dinv) {
    __shared__ int part[1024];
    int t = threadIdx.x;
    int base = t * 10;
    int s = 0;
#pragma unroll
    for (int k = 0; k < 10; ++k) {
        int b = base + k;
        if (b < N_NODES) s += cnt[b];
    }
    part[t] = s;
    __syncthreads();
    for (int off = 1; off < 1024; off <<= 1) {
        int v = 0;
        if (t >= off) v = part[t - off];
        __syncthreads();
        part[t] += v;
        __syncthreads();
    }
    int running = (t == 0) ? 0 : part[t - 1];
#pragma unroll
    for (int k = 0; k < 10; ++k) {
        int b = base + k;
        if (b < N_NODES) {
            row_ptr[b]  = running;
            fill_pos[b] = running;
            int c = cnt[b];
            dinv[b] = rsqrtf((float)c + 1.0f);
            running += c;
        }
    }
    if (t == 1023) row_ptr[N_NODES] = part[1023];
}

// ---------------- CSR bucket fill: edge record = {src byte offset, ne} -------
__global__ void fill_kernel(const int* __restrict__ src, const int* __restrict__ dst,
                            const float* __restrict__ dinv,
                            int* __restrict__ fill_pos,
                            int2* __restrict__ edges, int E) {
    int e = blockIdx.x * blockDim.x + threadIdx.x;
    if (e >= E) return;
    int s = src[e], d = dst[e];
    int pos = atomicAdd(&fill_pos[d], 1);
    edges[pos] = make_int2(s * (RSTRIDE * 4), __float_as_int(dinv[s] * dinv[d]));
}

// ---------------- transpose conv weights for coalesced lane reads ------------
__global__ void prep_kernel(const float* __restrict__ c1w, const float* __restrict__ c2w,
                            float* __restrict__ w1t, float* __restrict__ w2t) {
    int idx = blockIdx.x * blockDim.x + threadIdx.x;   // 8192 threads
    if (idx < 6144) {
        int tc = idx & 31, r = idx >> 5;               // r = ic*3+k
        w1t[idx] = c1w[tc * 192 + r];
    } else {
        int i2 = idx - 6144;
        int tc = i2 & 31, r = i2 >> 5;                 // r = ic*2+k
        int ic = r >> 1, k = r & 1;
        w2t[i2] = c2w[tc * 96 + ic * 3 + k];
    }
}

// ---------------- GEMM1 x3: m[bn][ch][t] = x_row(16, w=9+t) @ W1 -------------
__global__ __launch_bounds__(256) void gemm1_kernel(const float* __restrict__ x,
                                                    const float* __restrict__ W1,
                                                    float* __restrict__ m) {
    int idx = blockIdx.x * blockDim.x + threadIdx.x;
    int oc = idx & 63;
    int bn = __builtin_amdgcn_readfirstlane(idx >> 6);   // wave-uniform -> s_loads on x
    int b = bn / N_NODES, n = bn - b * N_NODES;
    const float* xb = x + ((size_t)b * NW) * N_NODES * IN_F + (size_t)n * IN_F;
    float s0 = 0.f, s1 = 0.f, s2 = 0.f;
#pragma unroll
    for (int f = 0; f < IN_F; ++f) {
        float wv = W1[f * HID + oc];
        s0 += xb[(size_t)9  * N_NODES * IN_F + f] * wv;
        s1 += xb[(size_t)10 * N_NODES * IN_F + f] * wv;
        s2 += xb[(size_t)11 * N_NODES * IN_F + f] * wv;
    }
    float* mr = m + (size_t)bn * RSTRIDE + oc * 3;       // contiguous triple
    mr[0] = s0; mr[1] = s1; mr[2] = s2;
}

// ---- gatherA x3: h1 = relu(agg(m1)+dinv^2*m1+b1); m2 = h1 @ W2 --------------
// One wave per row, lane = channel; each edge is ONE dwordx3 request (768B/wave).
__global__ __launch_bounds__(256, 8) void gatherA_kernel(
        const float* __restrict__ m, const int* __restrict__ row_ptr,
        const int2* __restrict__ edges,
        const float* __restrict__ dinv, const float* __restrict__ b1,
        const float* __restrict__ W2, float* __restrict__ m2) {
    __shared__ float hs[4][3][HID];
    int gid = blockIdx.x * blockDim.x + threadIdx.x;
    int lane = threadIdx.x & 63;
    int wv = threadIdx.x >> 6;
    int row = __builtin_amdgcn_readfirstlane(gid >> 6);  // -> s_loads on CSR
    const char* mrow = (const char*)m + (size_t)row * (RSTRIDE * 4);
    F3 self = *(const F3*)(mrow + lane * 12);
    float s0, s1, s2;
    if (row < N_NODES) {
        float dv = dinv[row];
        float sn = dv * dv;
        s0 = sn * self.x; s1 = sn * self.y; s2 = sn * self.z;
        int j = row_ptr[row], end = row_ptr[row + 1];
        for (; j + 3 < end; j += 4) {
            int2 e0 = edges[j], e1 = edges[j + 1], e2 = edges[j + 2], e3 = edges[j + 3];
            F3 v0 = *(const F3*)((const char*)m + e0.x + lane * 12);
            F3 v1 = *(const F3*)((const char*)m + e1.x + lane * 12);
            F3 v2 = *(const F3*)((const char*)m + e2.x + lane * 12);
            F3 v3 = *(const F3*)((const char*)m + e3.x + lane * 12);
            float w0 = __int_as_float(e0.y), w1 = __int_as_float(e1.y);
            float w2 = __int_as_float(e2.y), w3 = __int_as_float(e3.y);
            s0 += w0 * v0.x + w1 * v1.x + w2 * v2.x + w3 * v3.x;
            s1 += w0 * v0.y + w1 * v1.y + w2 * v2.y + w3 * v3.y;
            s2 += w0 * v0.z + w1 * v1.z + w2 * v2.z + w3 * v3.z;
        }
        for (; j < end; ++j) {
            int2 e = edges[j];
            F3 v = *(const F3*)((const char*)m + e.x + lane * 12);
            float w = __int_as_float(e.y);
            s0 += w * v.x; s1 += w * v.y; s2 += w * v.z;
        }
    } else {
        s0 = self.x; s1 = self.y; s2 = self.z;   // deg=1, no in-edges
    }
    float bb = b1[lane];
    hs[wv][0][lane] = fmaxf(s0 + bb, 0.f);
    hs[wv][1][lane] = fmaxf(s1 + bb, 0.f);
    hs[wv][2][lane] = fmaxf(s2 + bb, 0.f);
    __builtin_amdgcn_wave_barrier();
    float t0 = 0.f, t1 = 0.f, t2 = 0.f;
#pragma unroll
    for (int ic = 0; ic < HID; ++ic) {
        float w2v = W2[ic * HID + lane];
        t0 += hs[wv][0][ic] * w2v;
        t1 += hs[wv][1][ic] * w2v;
        t2 += hs[wv][2][ic] * w2v;
    }
    float* m2r = m2 + (size_t)row * RSTRIDE + lane * 3;
    m2r[0] = t0; m2r[1] = t1; m2r[2] = t2;
}

// ---- gatherBconv: H[t]=relu(agg+self+b2) t=9..11, conv1@10,11 + conv2@11 + fc
__global__ __launch_bounds__(256, 8) void gatherBconv_kernel(
        const float* __restrict__ m, const int* __restrict__ row_ptr,
        const int2* __restrict__ edges,
        const float* __restrict__ dinv, const float* __restrict__ b2,
        const float* __restrict__ w1t, const float* __restrict__ b1c,
        const float* __restrict__ w2t, const float* __restrict__ b2c,
        const float* __restrict__ fcw, const float* __restrict__ fcb,
        float* __restrict__ out) {
    __shared__ float hs[4][3][HID];      // per-wave H rows (t = 9,10,11)
    __shared__ float c1s[4][2][TCH];     // per-wave conv1 outputs (t = 10,11)
    int gid = blockIdx.x * blockDim.x + threadIdx.x;
    int lane = threadIdx.x & 63;
    int wv = threadIdx.x >> 6;
    int row = __builtin_amdgcn_readfirstlane(gid >> 6);
    const char* mrow = (const char*)m + (size_t)row * (RSTRIDE * 4);
    F3 self = *(const F3*)(mrow + lane * 12);
    float s0, s1, s2;
    if (row < N_NODES) {
        float dv = dinv[row];
        float sn = dv * dv;
        s0 = sn * self.x; s1 = sn * self.y; s2 = sn * self.z;
        int j = row_ptr[row], end = row_ptr[row + 1];
        for (; j + 3 < end; j += 4) {
            int2 e0 = edges[j], e1 = edges[j + 1], e2 = edges[j + 2], e3 = edges[j + 3];
            F3 v0 = *(const F3*)((const char*)m + e0.x + lane * 12);
            F3 v1 = *(const F3*)((const char*)m + e1.x + lane * 12);
            F3 v2 = *(const F3*)((const char*)m + e2.x + lane * 12);
            F3 v3 = *(const F3*)((const char*)m + e3.x + lane * 12);
            float w0 = __int_as_float(e0.y), w1 = __int_as_float(e1.y);
            float w2 = __int_as_float(e2.y), w3 = __int_as_float(e3.y);
            s0 += w0 * v0.x + w1 * v1.x + w2 * v2.x + w3 * v3.x;
            s1 += w0 * v0.y + w1 * v1.y + w2 * v2.y + w3 * v3.y;
            s2 += w0 * v0.z + w1 * v1.z + w2 * v2.z + w3 * v3.z;
        }
        for (; j < end; ++j) {
            int2 e = edges[j];
            F3 v = *(const F3*)((const char*)m + e.x + lane * 12);
            float w = __int_as_float(e.y);
            s0 += w * v.x; s1 += w * v.y; s2 += w * v.z;
        }
    } else {
        s0 = self.x; s1 = self.y; s2 = self.z;
    }
    float bb = b2[lane];
    hs[wv][0][lane] = fmaxf(s0 + bb, 0.f);   // H @ t=9
    hs[wv][1][lane] = fmaxf(s1 + bb, 0.f);   // H @ t=10
    hs[wv][2][lane] = fmaxf(s2 + bb, 0.f);   // H @ t=11
    __builtin_amdgcn_wave_barrier();

    // ---- conv1: lane (pos,tc) computes c1[10+pos][tc] ----
    int pos = lane >> 5, tc = lane & 31;
    float acc = b1c[tc];
#pragma unroll 8
    for (int ic = 0; ic < HID; ++ic) {
        float w0 = w1t[(ic * 3 + 0) * 32 + tc];
        float w1 = w1t[(ic * 3 + 1) * 32 + tc];
        float w2 = w1t[(ic * 3 + 2) * 32 + tc];
        float hA = hs[wv][pos][ic];                      // t = 9+pos
        float hB = hs[wv][pos + 1][ic];                  // t = 10+pos
        float hC = (pos == 0) ? hs[wv][2][ic] : 0.f;     // t = 11 (pad at pos=1)
        acc += hA * w0 + hB * w1 + hC * w2;
    }
    c1s[wv][pos][tc] = fmaxf(acc, 0.f);
    __builtin_amdgcn_wave_barrier();

    // ---- conv2 @ t=11 (+relu, *fcw) on lanes 0..31; wave reduce; fc ----
    float r = 0.f;
    if (pos == 0) {
        float a2 = b2c[tc];
#pragma unroll 8
        for (int ic = 0; ic < TCH; ++ic) {
            a2 += c1s[wv][0][ic] * w2t[(ic * 2 + 0) * 32 + tc]
                + c1s[wv][1][ic] * w2t[(ic * 2 + 1) * 32 + tc];
        }
        r = fmaxf(a2, 0.f) * fcw[tc];
    }
#pragma unroll
    for (int off = 32; off > 0; off >>= 1) r += __shfl_down(r, off);
    if (lane == 0) out[row] = r + fcb[0];
}

extern "C" void kernel_launch(void* const* d_in, const int* in_sizes, int n_in,
                              void* d_out, int out_size, void* d_ws, size_t ws_size,
                              hipStream_t stream) {
    const float* x   = (const float*)d_in[0];
    const int*   ei  = (const int*)d_in[1];
    const float* W1  = (const float*)d_in[2];
    const float* b1  = (const float*)d_in[3];
    const float* W2  = (const float*)d_in[4];
    const float* b2  = (const float*)d_in[5];
    const float* c1w = (const float*)d_in[6];
    const float* c1b = (const float*)d_in[7];
    const float* c2w = (const float*)d_in[8];
    const float* c2b = (const float*)d_in[9];
    const float* fcw = (const float*)d_in[10];
    const float* fcb = (const float*)d_in[11];
    float* out = (float*)d_out;

    const int E = in_sizes[1] / 2;
    const int* src = ei;
    const int* dst = ei + E;

    // ---- workspace layout ----
    const size_t S3 = (size_t)BN_TOT * RSTRIDE;    // 7,680,000 floats per m-buffer
    int*   cnt      = (int*)d_ws;                  // 10240
    int*   row_ptr  = cnt + 10240;                 // 10240
    int*   fill_pos = row_ptr + 10240;             // 10240
    int2*  edges    = (int2*)(fill_pos + 10240);   // E records (8 B each)
    float* dinv     = (float*)(edges + E);         // 10240
    float* w1t      = dinv + 10240;                // 6144
    float* w2t      = w1t + 6144;                  // 2048
    float* mA       = w2t + 2048;                  // S3
    float* mB       = mA + S3;                     // S3

    // ---- CSR build + weight transpose ----
    hipMemsetAsync(cnt, 0, N_NODES * sizeof(int), stream);
    hist_kernel<<<(E + 255) / 256, 256, 0, stream>>>(dst, cnt, E);
    scan_kernel<<<1, 1024, 0, stream>>>(cnt, row_ptr, fill_pos, dinv);
    fill_kernel<<<(E + 255) / 256, 256, 0, stream>>>(src, dst, dinv, fill_pos, edges, E);
    prep_kernel<<<32, 256, 0, stream>>>(c1w, c2w, w1t, w2t);

    const int NT = BN_TOT * HID;                   // 2,560,000 threads = 10000 blocks
    gemm1_kernel <<<NT / 256, 256, 0, stream>>>(x, W1, mA);
    gatherA_kernel<<<NT / 256, 256, 0, stream>>>(mA, row_ptr, edges, dinv, b1, W2, mB);
    gatherBconv_kernel<<<NT / 256, 256, 0, stream>>>(mB, row_ptr, edges, dinv, b2,
                                                     w1t, c1b, w2t, c2b, fcw, fcb, out);
}